// Round 4
// baseline (163.897 us; speedup 1.0000x reference)
//
#include <hip/hip_runtime.h>
#include <hip/hip_fp16.h>
#include <math.h>

// CTC loss forward, single fused kernel. One block (4 waves) per batch element.
// Beta-transform: beta[s,t] = alpha[s,t] - cum_blank(t). Then:
//   - state 0: beta == 0 always (DPP fill constant)
//   - even (blank) states: nE = logaddexp2(aE, aO)            (no per-step add)
//   - odd (label) states:  nO = lae3(aO, pE, skip*pO) + d[t,l]
// where d[t,l] = (x[b,t,lab_l] - x[b,t,blank]) / ln2  -- the LSE cancels!
// LSE survives only in cum_blank = sum_{t<inlen} (x_blank/ln2 - lse2), restored
// at readout. Phase 1 (4 waves): stream y_pred coalesced, bpermute-gather d
// into 64 KB LDS (fp16 [T/8][64][8]), lse butterfly -> lpb to global ws.
// Phase 2 (wave 0): 512-step chain, 1 ds_read_b128 per 8 steps, DPP shifts.
// B=256, T=512, C=128 (blank=127), L=64, S=129.

#define NEGV (-1e30f)

constexpr int Cc = 128;
constexpr int Tt = 512;
constexpr int Ll = 64;
constexpr float INV_LN2 = 1.4426950408889634f;
constexpr float LN2_F   = 0.6931471805599453f;

__device__ __forceinline__ float fexp2(float x) { return __builtin_amdgcn_exp2f(x); }
__device__ __forceinline__ float flog2(float x) { return __builtin_amdgcn_logf(x); }

// Whole-wave shift right by 1 lane (lane i <- lane i-1); lane 0 <- fill.
__device__ __forceinline__ float wave_shr1(float x, float fill) {
    return __int_as_float(__builtin_amdgcn_update_dpp(
        __float_as_int(fill), __float_as_int(x), 0x138, 0xF, 0xF, false));
}
__device__ __forceinline__ float bperm(int lane, float v) {
    return __int_as_float(__builtin_amdgcn_ds_bpermute(lane << 2, __float_as_int(v)));
}

__global__ __launch_bounds__(256, 1) void ctc_fused_kernel(
    const int* __restrict__ y_true,      // [B, 64]
    const float* __restrict__ y_pred,    // [B, T, C]
    const int* __restrict__ in_len,      // [B]
    const int* __restrict__ lab_len,     // [B]
    float* __restrict__ lpb_ws,          // [B, T] scratch: lp2_blank per (b,t)
    float* __restrict__ out)             // [B]
{
    __shared__ __half d_lds[Tt / 8][64][8];   // [t>>3][lane][t&7], 64 KB exactly

    const int b   = blockIdx.x;
    const int tid = threadIdx.x;
    const int w   = tid >> 6;            // wave 0..3
    const int l   = tid & 63;

    const int lab = y_true[b * Ll + l] & 127;   // label for odd state 2l+1
    const float* rowbase = y_pred + (size_t)b * Tt * Cc;
    float* lpb = lpb_ws + b * Tt;

    // ---------------- Phase 1: wave w handles rows [w*128, w*128+128) ----------------
    // float4 half-split: lanes 0-31 hold row rA (128 floats), lanes 32-63 row rB=rA+1.
    const int half = l >> 5, li = l & 31;
    const int srcA = lab >> 2;           // source lane (within half0) holding lab
    const int csel = lab & 3;
    const int tbase = w * 128;

    float4 vb[4];
#pragma unroll
    for (int j = 0; j < 4; ++j)
        vb[j] = ((const float4*)(rowbase + (size_t)(tbase + 2 * j + half) * Cc))[li];

    for (int i = 0; i < 64; i += 4) {
#pragma unroll
        for (int j = 0; j < 4; ++j) {
            const float4 v = vb[j];
            const int nx = i + 4 + j;
            if (nx < 64)
                vb[j] = ((const float4*)(rowbase + (size_t)(tbase + 2 * nx + half) * Cc))[li];

            const int rA = tbase + 2 * (i + j);
            const int rB = rA + 1;

            // lse butterfly within each 32-lane half (2 rows at once)
            float e = (fexp2(v.x * INV_LN2) + fexp2(v.y * INV_LN2))
                    + (fexp2(v.z * INV_LN2) + fexp2(v.w * INV_LN2));
#pragma unroll
            for (int off = 1; off < 32; off <<= 1) e += __shfl_xor(e, off, 64);
            const float ls = flog2(e);                       // valid on lanes 31 / 63
            if (li == 31) lpb[half ? rB : rA] = fmaf(v.w, INV_LN2, -ls);

            // blank logits (class 127 = lane 31/63's v.w), broadcast
            const float blA = __shfl(v.w, 31, 64);
            const float blB = __shfl(v.w, 63, 64);

            // gather x[row, lab_l] for both rows via bpermute + component select
            float gx = bperm(srcA, v.x), gy = bperm(srcA, v.y);
            float gz = bperm(srcA, v.z), gw = bperm(srcA, v.w);
            const float xA = (csel & 2) ? ((csel & 1) ? gw : gz)
                                        : ((csel & 1) ? gy : gx);
            gx = bperm(srcA + 32, v.x); gy = bperm(srcA + 32, v.y);
            gz = bperm(srcA + 32, v.z); gw = bperm(srcA + 32, v.w);
            const float xB = (csel & 2) ? ((csel & 1) ? gw : gz)
                                        : ((csel & 1) ? gy : gx);

            d_lds[rA >> 3][l][rA & 7] = __float2half((xA - blA) * INV_LN2);
            d_lds[rB >> 3][l][rB & 7] = __float2half((xB - blB) * INV_LN2);
        }
    }

    __syncthreads();
    if (w != 0) return;

    // ---------------- Phase 2: wave 0 runs the 512-step chain ----------------
    const int inlen = in_len[b];         // [T/2, T]
    const int LLv   = lab_len[b];        // [L/2, L]

    const int labp  = __shfl_up(lab, 1, 64);
    const float skf = ((l >= 1) && (lab != labp)) ? 1.0f : 0.0f;

    float aO = NEGV, aE = NEGV;          // beta[2l+1], beta[2l+2]

#define CTC_STEP(DJ) {                                                   \
        const float pE = wave_shr1(aE, 0.0f);   /* beta[2l]; lane0: state0=0 */ \
        const float pO = wave_shr1(aO, NEGV);   /* beta[2l-1] */          \
        const float M  = fmaxf(fmaxf(aO, pE), pO);                        \
        const float sm = fexp2(aO - M) + fexp2(pE - M) + skf * fexp2(pO - M); \
        const float nO = flog2(sm) + M + (DJ);                            \
        const float m2 = fmaxf(aE, aO);                                   \
        const float nE = flog2(fexp2(aE - m2) + fexp2(aO - m2)) + m2;     \
        aO = nO; aE = nE; }

    // chunk pipeline: raw __half2 regs, convert at consume (hides ds latency)
    __half2 hA[4], hB[4];
    {
        const __half2* p = reinterpret_cast<const __half2*>(&d_lds[0][l][0]);
#pragma unroll
        for (int q = 0; q < 4; ++q) hA[q] = p[q];
    }

    const int nfull = inlen >> 3;        // >= 32 for this data
    for (int cb = 0; cb < nfull; ++cb) {
        int nx = cb + 1; if (nx > (Tt / 8 - 1)) nx = Tt / 8 - 1;
        const __half2* p = reinterpret_cast<const __half2*>(&d_lds[nx][l][0]);
#pragma unroll
        for (int q = 0; q < 4; ++q) hB[q] = p[q];
#pragma unroll
        for (int j = 0; j < 8; ++j) {
            const float dj = (j & 1) ? __high2float(hA[j >> 1]) : __low2float(hA[j >> 1]);
            CTC_STEP(dj);
        }
#pragma unroll
        for (int q = 0; q < 4; ++q) hA[q] = hB[q];
    }
    const int t0 = nfull << 3;
    if (t0 < inlen) {                    // tail chunk (hA holds chunk nfull)
#pragma unroll
        for (int j = 0; j < 8; ++j) {
            if (t0 + j < inlen) {
                const float dj = (j & 1) ? __high2float(hA[j >> 1]) : __low2float(hA[j >> 1]);
                CTC_STEP(dj);
            }
        }
    }
#undef CTC_STEP

    // cum_blank = sum_{t<inlen} lp2b(t)  (parallel over lanes, butterfly reduce)
    float s = 0.0f;
#pragma unroll
    for (int j = 0; j < 8; ++j) {
        const int idx = j * 64 + l;
        const float vv = lpb[idx];
        s += (idx < inlen) ? vv : 0.0f;
    }
#pragma unroll
    for (int off = 1; off < 64; off <<= 1) s += __shfl_xor(s, off, 64);

    // readout: states 2*LL (aE) and 2*LL-1 (aO) live on lane LL-1
    const float aEr = __shfl(aE, LLv - 1, 64);
    const float aOr = __shfl(aO, LLv - 1, 64);
    if (l == 0) {
        const float m = fmaxf(aEr, aOr);
        const float lv = m + flog2(fexp2(aEr - m) + fexp2(aOr - m));
        out[b] = -LN2_F * (lv + s);
    }
}

extern "C" void kernel_launch(void* const* d_in, const int* in_sizes, int n_in,
                              void* d_out, int out_size, void* d_ws, size_t ws_size,
                              hipStream_t stream) {
    const int*   y_true  = (const int*)d_in[0];    // [256,64]
    const float* y_pred  = (const float*)d_in[1];  // [256,512,128]
    const int*   in_len  = (const int*)d_in[2];    // [256]
    const int*   lab_len = (const int*)d_in[3];    // [256]
    float*       out     = (float*)d_out;          // [256]
    float*       lpb_ws  = (float*)d_ws;           // [256*512] fp32 = 512 KB

    ctc_fused_kernel<<<256, 256, 0, stream>>>(y_true, y_pred, in_len, lab_len, lpb_ws, out);
}

// Round 6
// 128.853 us; speedup vs baseline: 1.2720x; 1.2720x over previous
//
#include <hip/hip_runtime.h>
#include <hip/hip_fp16.h>
#include <math.h>

// CTC loss forward, single fused kernel, LINEAR-domain recurrence (beta transform).
// One block (4 waves) per batch element (B=256 = CU count).
//   beta[s,t] = alpha[s,t] - cum_blank(t)  =>  blank transitions have weight 1:
//     nO = (aO + pE + skip*pO) * w,  w = e^{x_lab - x_blank}   (label states)
//     nE = aE + aO                                             (blank states)
//     state0 = r0 (constant 1 modulo renorms)
//   Per-step serial chain: 2 DPP wave_shr:1 + fma + add + mul  (~20 cyc), no
//   transcendentals (round-4 lesson) and no DS ops (round-2 lesson).
// Range control (round-5 lesson: lagged renorm + unproven row_bcast DPP modes
// produced inf): ZERO-LAG renorm every 8 steps using only textbook pieces --
// row_shr DPP partial max + v_readlane of lanes 15/31/47/63 + uniform max.
// Post-renorm max in [1,2); 8-step growth <= (3*2^13)^8 = 2^117 (w clamped)
// so fp32 can never overflow; R>=0 clamp, state cap 4.0 (no-op when healthy),
// readout floor 1e-37 (kills log2(0)).
// B=256, T=512, C=128 (blank=127), L=64, S=129.

constexpr int Cc = 128;
constexpr int Tt = 512;
constexpr int Ll = 64;
constexpr float INV_LN2 = 1.4426950408889634f;
constexpr float LN2_F   = 0.6931471805599453f;

__device__ __forceinline__ float fexp2(float x) { return __builtin_amdgcn_exp2f(x); }
__device__ __forceinline__ float flog2(float x) { return __builtin_amdgcn_logf(x); }

template<int CTRL, bool BC>
__device__ __forceinline__ float dppf(float old, float x) {
    return __int_as_float(__builtin_amdgcn_update_dpp(
        __float_as_int(old), __float_as_int(x), CTRL, 0xF, 0xF, BC));
}
// lane i <- lane i-1 across whole wave; lane 0 <- fill. (silicon-proven r3/r4)
__device__ __forceinline__ float wshr1(float x, float fill) { return dppf<0x138, false>(fill, x); }

__device__ __forceinline__ float rlf(float v, int lane) {
    return __int_as_float(__builtin_amdgcn_readlane(__float_as_int(v), lane));
}

// Row-local (16-lane) suffix reduce: lanes 15/31/47/63 hold their row's result.
__device__ __forceinline__ float rowsum(float e) {
    e += dppf<0x111, true>(0.f, e);   // row_shr:1, 0-fill
    e += dppf<0x112, true>(0.f, e);   // row_shr:2
    e += dppf<0x114, true>(0.f, e);   // row_shr:4
    e += dppf<0x118, true>(0.f, e);   // row_shr:8
    return e;
}
__device__ __forceinline__ float rowmax(float m) {   // m >= 0 required (0-fill)
    m = fmaxf(m, dppf<0x111, true>(0.f, m));
    m = fmaxf(m, dppf<0x112, true>(0.f, m));
    m = fmaxf(m, dppf<0x114, true>(0.f, m));
    m = fmaxf(m, dppf<0x118, true>(0.f, m));
    return m;
}
// Uniform combine of the four row results via readlane (no row_bcast modes).
__device__ __forceinline__ float allsum(float e) {
    e = rowsum(e);
    return (rlf(e, 15) + rlf(e, 31)) + (rlf(e, 47) + rlf(e, 63));
}
__device__ __forceinline__ float allmax(float m) {
    m = rowmax(m);
    return fmaxf(fmaxf(rlf(m, 15), rlf(m, 31)), fmaxf(rlf(m, 47), rlf(m, 63)));
}

__device__ __forceinline__ float bperm_f(int srclane, float v) {
    return __int_as_float(__builtin_amdgcn_ds_bpermute(srclane << 2, __float_as_int(v)));
}
__device__ __forceinline__ float gather4(float4 v, int srclane, int csel) {
    const float gx = bperm_f(srclane, v.x), gy = bperm_f(srclane, v.y);
    const float gz = bperm_f(srclane, v.z), gw = bperm_f(srclane, v.w);
    const float lo = (csel & 1) ? gy : gx;
    const float hi = (csel & 1) ? gw : gz;
    return (csel & 2) ? hi : lo;
}

__global__ __launch_bounds__(256, 1) void ctc_fused_kernel(
    const int* __restrict__ y_true,      // [B, 64]
    const float* __restrict__ y_pred,    // [B, T, C]
    const int* __restrict__ in_len,      // [B]
    const int* __restrict__ lab_len,     // [B]
    float* __restrict__ lpb_ws,          // [B, T] scratch: lp2_blank
    float* __restrict__ out)             // [B]
{
    __shared__ __half w_lds[Tt * 64];    // w[t][lane], 64 KB, lane-inner (conflict-free)

    const int b   = blockIdx.x;
    const int tid = threadIdx.x;
    const int w   = tid >> 6;            // wave 0..3
    const int l   = tid & 63;

    const int lab = y_true[b * Ll + l] & 127;
    const float* rowbase = y_pred + (size_t)b * Tt * Cc;
    float* lpb = lpb_ws + b * Tt;

    // ---------------- Phase 1: wave w -> rows [w*128, w*128+128) ----------------
    const int half = l >> 5, li = l & 31;
    const int srcA = lab >> 2;           // lane (in low half) holding class `lab`
    const int csel = lab & 3;
    const int tbase = w * 128;

    float4 vb[4];
#pragma unroll
    for (int j = 0; j < 4; ++j)
        vb[j] = ((const float4*)(rowbase + (size_t)(tbase + 2 * j + half) * Cc))[li];

    for (int i = 0; i < 64; i += 4) {
#pragma unroll
        for (int j = 0; j < 4; ++j) {
            const float4 v = vb[j];
            const int nx = i + 4 + j;
            if (nx < 64)
                vb[j] = ((const float4*)(rowbase + (size_t)(tbase + 2 * nx + half) * Cc))[li];

            const int rA = tbase + 2 * (i + j);
            const int rB = rA + 1;

            // lse: row sums via row_shr chain; uniform combine per 32-lane half
            float e = (fexp2(v.x * INV_LN2) + fexp2(v.y * INV_LN2))
                    + (fexp2(v.z * INV_LN2) + fexp2(v.w * INV_LN2));
            e = rowsum(e);
            const float sA = rlf(e, 15) + rlf(e, 31);   // row A total (lanes 0-31)
            const float sB = rlf(e, 47) + rlf(e, 63);   // row B total (lanes 32-63)
            const float lsA = flog2(sA), lsB = flog2(sB);

            // blank logits: class 127 = v.w of lanes 31 / 63 (uniform)
            const float blA = rlf(v.w, 31);
            const float blB = rlf(v.w, 63);

            if (l == 0) {
                lpb[rA] = fmaf(blA, INV_LN2, -lsA);
                lpb[rB] = fmaf(blB, INV_LN2, -lsB);
            }

            // per-lane label logits (round-4-proven bpermute gather); clamp w
            const float xA = gather4(v, srcA, csel);
            const float xB = gather4(v, srcA + 32, csel);
            const float wA = fminf(fmaxf(fexp2((xA - blA) * INV_LN2), 6.1e-5f), 8192.0f);
            const float wB = fminf(fmaxf(fexp2((xB - blB) * INV_LN2), 6.1e-5f), 8192.0f);
            w_lds[rA * 64 + l] = __float2half(wA);
            w_lds[rB * 64 + l] = __float2half(wB);
        }
    }

    __syncthreads();
    if (w != 0) return;

    // ---------------- Phase 2: wave 0, linear-domain chain ----------------
    const int inlen = in_len[b];         // [T/2, T]
    const int LLv   = lab_len[b];        // [L/2, L]

    const int labp  = __shfl_up(lab, 1, 64);
    const float skf = ((l >= 1) && (lab != labp)) ? 1.0f : 0.0f;

    // cum_blank inputs: load early, reduce at the end
    float cb8[8];
#pragma unroll
    for (int j = 0; j < 8; ++j) cb8[j] = lpb[j * 64 + l];

    // state: aO = beta[2l+1], aE = beta[2l+2], r0 = beta[0] (linear, >= 0)
    float aO = 0.0f, aE = 0.0f, r0 = 1.0f;
    float Rtot = 0.0f;

#define STEP(W) {                                                         \
        const float pE = wshr1(aE, r0);      /* beta[2l]; lane0: state0 */\
        const float pO = wshr1(aO, 0.0f);    /* beta[2l-1] */             \
        const float nO = (fmaf(skf, pO, pE) + aO) * (W);                  \
        aE += aO;                                                         \
        aO = nO; }

    // zero-lag renorm: measure AND apply now; max>=1 guaranteed => R>=0.
#define RENORM() {                                                        \
        const float M_ = allmax(fmaxf(fmaxf(aO, aE), r0));                \
        int R_ = (int)(__float_as_uint(M_) >> 23) - 127;                  \
        R_ = (R_ < 0) ? 0 : ((R_ > 126) ? 126 : R_);                      \
        const float sc = __uint_as_float((unsigned)(127 - R_) << 23);     \
        aO = fminf(aO * sc, 4.0f);                                        \
        aE = fminf(aE * sc, 4.0f);                                        \
        r0 = fminf(r0 * sc, 4.0f);                                        \
        Rtot += (float)R_; }

    __half hA[8], hB[8];
#pragma unroll
    for (int q = 0; q < 8; ++q) hA[q] = w_lds[q * 64 + l];

    const int nfull = inlen >> 3;        // >= 32
    for (int cb = 0; cb < nfull; ++cb) {
        const int nx = (cb + 1 < Tt / 8) ? cb + 1 : Tt / 8 - 1;
#pragma unroll
        for (int q = 0; q < 8; ++q) hB[q] = w_lds[(nx * 8 + q) * 64 + l];
#pragma unroll
        for (int j = 0; j < 8; ++j) STEP(__half2float(hA[j]));
        RENORM();
#pragma unroll
        for (int q = 0; q < 8; ++q) hA[q] = hB[q];
    }
    const int t0 = nfull << 3;
    if (t0 < inlen) {                    // <= 7 extra steps: growth-safe, no renorm
#pragma unroll
        for (int j = 0; j < 8; ++j)
            if (t0 + j < inlen) STEP(__half2float(hA[j]));
    }
#undef STEP
#undef RENORM

    // cum_blank = sum_{t<inlen} lp2b(t)  (row_shr + readlane combine, uniform)
    float s = 0.0f;
#pragma unroll
    for (int j = 0; j < 8; ++j) s += (j * 64 + l < inlen) ? cb8[j] : 0.0f;
    const float cum_b = allsum(s);

    // readout: states 2*LL (aE) and 2*LL-1 (aO) live on lane LL-1.
    // alpha_log2 = log2(beta_lin) + Rtot + cum_b.
    const float aEr = __shfl(aE, LLv - 1, 64);
    const float aOr = __shfl(aO, LLv - 1, 64);
    if (l == 0)
        out[b] = -LN2_F * (flog2(fmaxf(aEr + aOr, 1e-37f)) + Rtot + cum_b);
}

extern "C" void kernel_launch(void* const* d_in, const int* in_sizes, int n_in,
                              void* d_out, int out_size, void* d_ws, size_t ws_size,
                              hipStream_t stream) {
    const int*   y_true  = (const int*)d_in[0];    // [256,64]
    const float* y_pred  = (const float*)d_in[1];  // [256,512,128]
    const int*   in_len  = (const int*)d_in[2];    // [256]
    const int*   lab_len = (const int*)d_in[3];    // [256]
    float*       out     = (float*)d_out;          // [256]
    float*       lpb_ws  = (float*)d_ws;           // [256*512] fp32 = 512 KB

    ctc_fused_kernel<<<256, 256, 0, stream>>>(y_true, y_pred, in_len, lab_len, lpb_ws, out);
}